// Round 1
// baseline (2222.375 us; speedup 1.0000x reference)
//
#include <hip/hip_runtime.h>
#include <math.h>

#define BATCH 32
#define NA 100000
#define NC 81
#define NBUCK 32768
#define NEG_RATIO 3

// ---------------------------------------------------------------------------
// k1: per anchor -- logsumexp over 81 classes, positive (smooth-L1 + CE)
// accumulation per sample, negative value -> ws array + 32768-bucket histogram
// (float bits are monotone for v>=0, bucket = bits>>17).
// ---------------------------------------------------------------------------
__global__ __launch_bounds__(256) void k1_main(
    const float* __restrict__ loc_p, const float* __restrict__ cls_p,
    const float* __restrict__ loc_t, const int* __restrict__ cls_t,
    float* __restrict__ neg_vals, int* __restrict__ hist,
    int* __restrict__ pos_count, float* __restrict__ sl1_sum,
    float* __restrict__ ce_sum)
{
    const int b = blockIdx.y;
    const int a = blockIdx.x * blockDim.x + threadIdx.x;

    float my_sl1 = 0.0f, my_ce = 0.0f;
    int my_pos = 0;

    if (a < NA) {
        const size_t idx = (size_t)b * NA + a;
        const float* __restrict__ x = cls_p + idx * NC;

        // online log-sum-exp in 5 chunks of 16 + 1 tail (keeps VGPRs ~16)
        float m = -3.0e38f, s = 0.0f;
        #pragma unroll
        for (int c = 0; c < 5; ++c) {
            float r[16];
            #pragma unroll
            for (int j = 0; j < 16; ++j) r[j] = x[c * 16 + j];
            float cm = r[0];
            #pragma unroll
            for (int j = 1; j < 16; ++j) cm = fmaxf(cm, r[j]);
            const float nm = fmaxf(m, cm);
            float cs = 0.0f;
            #pragma unroll
            for (int j = 0; j < 16; ++j) cs += __expf(r[j] - nm);
            s = s * __expf(m - nm) + cs;
            m = nm;
        }
        {
            const float x80 = x[80];
            const float nm = fmaxf(m, x80);
            s = s * __expf(m - nm) + __expf(x80 - nm);
            m = nm;
        }
        const float lse = m + __logf(s);

        const int t = cls_t[idx];
        if (t != 0) {
            my_pos = 1;
            my_ce = lse - x[t];
            const float4 lp = *(const float4*)(loc_p + idx * 4);
            const float4 lt = *(const float4*)(loc_t + idx * 4);
            float d, ad;
            d = lp.x - lt.x; ad = fabsf(d);
            my_sl1 += (ad < 1.0f) ? 0.5f * d * d : ad - 0.5f;
            d = lp.y - lt.y; ad = fabsf(d);
            my_sl1 += (ad < 1.0f) ? 0.5f * d * d : ad - 0.5f;
            d = lp.z - lt.z; ad = fabsf(d);
            my_sl1 += (ad < 1.0f) ? 0.5f * d * d : ad - 0.5f;
            d = lp.w - lt.w; ad = fabsf(d);
            my_sl1 += (ad < 1.0f) ? 0.5f * d * d : ad - 0.5f;
            neg_vals[idx] = -1.0f;   // sentinel: not a negative
        } else {
            const float v = fmaxf(lse - x[0], 0.0f);
            neg_vals[idx] = v;
            atomicAdd(&hist[b * NBUCK + (int)(__float_as_uint(v) >> 17)], 1);
        }
    }

    // wave -> block reduction of (pos, sl1, ce); 3 atomics per block
    for (int off = 32; off > 0; off >>= 1) {
        my_sl1 += __shfl_down(my_sl1, off);
        my_ce  += __shfl_down(my_ce, off);
        my_pos += __shfl_down(my_pos, off);
    }
    __shared__ float rs[4], rc[4];
    __shared__ int rp[4];
    const int wave = threadIdx.x >> 6, lane = threadIdx.x & 63;
    if (lane == 0) { rs[wave] = my_sl1; rc[wave] = my_ce; rp[wave] = my_pos; }
    __syncthreads();
    if (threadIdx.x == 0) {
        const float a0 = rs[0] + rs[1] + rs[2] + rs[3];
        const float a1 = rc[0] + rc[1] + rc[2] + rc[3];
        const int   p  = rp[0] + rp[1] + rp[2] + rp[3];
        if (p) atomicAdd(&pos_count[b], p);
        if (a0 != 0.0f) atomicAdd(&sl1_sum[b], a0);
        if (a1 != 0.0f) atomicAdd(&ce_sum[b], a1);
    }
}

// ---------------------------------------------------------------------------
// k2: per sample -- find threshold bucket T (from the top) such that
// count(buckets > T) < k <= count(buckets >= T); store T and k_rem.
// ---------------------------------------------------------------------------
__global__ __launch_bounds__(256) void k2_select(
    const int* __restrict__ hist, const int* __restrict__ pos_count,
    int* __restrict__ Tbuck, int* __restrict__ krem)
{
    const int b = blockIdx.x;
    const int* __restrict__ h = hist + (size_t)b * NBUCK;
    __shared__ int chunk_sum[256];
    const int t = threadIdx.x;
    const int CH = NBUCK / 256;  // 128 buckets per thread
    int cs = 0;
    for (int j = 0; j < CH; ++j) cs += h[t * CH + j];
    chunk_sum[t] = cs;
    __syncthreads();

    if (t == 0) {
        const int np = pos_count[b];
        const int k = (np > 0) ? min(NEG_RATIO * np, NA - np) : 0;
        if (k <= 0) {
            Tbuck[b] = 0x7fffffff;  // nothing qualifies
            krem[b] = 0;
        } else {
            int cum = 0;
            int c = 255;
            for (; c >= 0; --c) {
                if (cum + chunk_sum[c] >= k) break;
                cum += chunk_sum[c];
            }
            if (c < 0) {
                // k >= total negatives: take everything
                Tbuck[b] = 0;
                krem[b] = 0x7fffffff;
            } else {
                int T = 0;
                for (int j = CH - 1; j >= 0; --j) {
                    const int bi = c * CH + j;
                    if (cum + h[bi] >= k) { T = bi; break; }
                    cum += h[bi];
                }
                Tbuck[b] = T;
                krem[b] = k - cum;  // how many to take from bucket T
            }
        }
    }
}

// ---------------------------------------------------------------------------
// k3: sum negatives with bucket > T; take exactly k_rem from bucket == T via
// atomic ticket counter (ties within one bucket differ by < bucket width).
// ---------------------------------------------------------------------------
__global__ __launch_bounds__(256) void k3_negsum(
    const float* __restrict__ neg_vals, const int* __restrict__ Tbuck,
    const int* __restrict__ krem, int* __restrict__ tie_cnt,
    float* __restrict__ neg_sum)
{
    const int b = blockIdx.y;
    const int a = blockIdx.x * blockDim.x + threadIdx.x;
    float add = 0.0f;
    if (a < NA) {
        const float v = neg_vals[(size_t)b * NA + a];
        if (v >= 0.0f) {
            const int buck = (int)(__float_as_uint(v) >> 17);
            const int T = Tbuck[b];
            if (buck > T) {
                add = v;
            } else if (buck == T) {
                const int old = atomicAdd(&tie_cnt[b], 1);
                if (old < krem[b]) add = v;
            }
        }
    }
    for (int off = 32; off > 0; off >>= 1) add += __shfl_down(add, off);
    if ((threadIdx.x & 63) == 0 && add != 0.0f) atomicAdd(&neg_sum[b], add);
}

// ---------------------------------------------------------------------------
// k4: combine per-sample pieces -> scalar output.
// ---------------------------------------------------------------------------
__global__ void k4_final(
    const int* __restrict__ pos_count, const float* __restrict__ sl1_sum,
    const float* __restrict__ ce_sum, const float* __restrict__ neg_sum,
    float* __restrict__ out)
{
    const int b = threadIdx.x;
    float v = 0.0f;
    if (b < BATCH) {
        const int np = pos_count[b];
        if (np > 0) {
            v = (sl1_sum[b] + ce_sum[b] + neg_sum[b]) / (float)np;
        }
    }
    for (int off = 32; off > 0; off >>= 1) v += __shfl_down(v, off);
    if (threadIdx.x == 0) out[0] = v;
}

extern "C" void kernel_launch(void* const* d_in, const int* in_sizes, int n_in,
                              void* d_out, int out_size, void* d_ws, size_t ws_size,
                              hipStream_t stream)
{
    const float* loc_p = (const float*)d_in[0];
    const float* cls_p = (const float*)d_in[1];
    const float* loc_t = (const float*)d_in[2];
    const int*   cls_t = (const int*)d_in[3];
    float* out = (float*)d_out;

    // workspace layout
    char* base = (char*)d_ws;
    float* neg_vals = (float*)base;
    size_t off = (size_t)BATCH * NA * sizeof(float);              // 12.8 MB
    int* hist = (int*)(base + off);
    off += (size_t)BATCH * NBUCK * sizeof(int);                   // 4 MB
    int*   pos_count = (int*)(base + off);   off += BATCH * sizeof(int);
    float* sl1_sum   = (float*)(base + off); off += BATCH * sizeof(float);
    float* ce_sum    = (float*)(base + off); off += BATCH * sizeof(float);
    float* neg_sum   = (float*)(base + off); off += BATCH * sizeof(float);
    int*   tie_cnt   = (int*)(base + off);   off += BATCH * sizeof(int);
    int*   Tbuck     = (int*)(base + off);   off += BATCH * sizeof(int);
    int*   krem      = (int*)(base + off);   off += BATCH * sizeof(int);

    // zero histogram + accumulators (contiguous region: hist..tie_cnt)
    const size_t zero_bytes =
        (size_t)BATCH * NBUCK * sizeof(int) + (size_t)5 * BATCH * sizeof(int);
    hipMemsetAsync(hist, 0, zero_bytes, stream);

    dim3 grid1((NA + 255) / 256, BATCH);
    k1_main<<<grid1, 256, 0, stream>>>(loc_p, cls_p, loc_t, cls_t,
                                       neg_vals, hist, pos_count, sl1_sum, ce_sum);
    k2_select<<<BATCH, 256, 0, stream>>>(hist, pos_count, Tbuck, krem);
    k3_negsum<<<grid1, 256, 0, stream>>>(neg_vals, Tbuck, krem, tie_cnt, neg_sum);
    k4_final<<<1, 64, 0, stream>>>(pos_count, sl1_sum, ce_sum, neg_sum, out);
}